// Round 13
// baseline (265.031 us; speedup 1.0000x reference)
//
#include <hip/hip_runtime.h>
#include <hip/hip_bf16.h>

typedef __attribute__((ext_vector_type(8))) short short8;
typedef __attribute__((ext_vector_type(4))) short short4v;
typedef __attribute__((ext_vector_type(4))) float f32x4;

__device__ __forceinline__ short f2bf(float f) {
  union { __hip_bfloat16 h; short s; } u;
  u.h = __float2bfloat16(f);
  return u.s;
}

// async 16B global->LDS DMA: LDS dst = wave-uniform base + lane*16 (m104);
// global src per-lane.
__device__ __forceinline__ void gll16(const void* g, void* l) {
  __builtin_amdgcn_global_load_lds(
      (const __attribute__((address_space(1))) void*)g,
      (__attribute__((address_space(3))) void*)l, 16, 0, 0);
}

#define SCHED_FENCE() __builtin_amdgcn_sched_barrier(0)
#define EPS 68   // epilogue f32 row stride

// C[512, N] = A_bf16[512, K] * W_f32[N, K]^T + bias.  BN=64, BK=32.
// 8 waves; wave w owns rows [w*64..w*64+64); waves share the W panel.
// W streams via global_load_lds into a 4-slot LDS ring (8KB/slot), issued
// 3 iters ahead. A lives in REGISTERS (aA/aB, 2-iter flight) -- R12 showed
// A-through-LDS doubles LDS traffic (136KB/iter) and its 64B-row layout
// 4-way-conflicts (12.5M cycles). Queue order per iter:
//   wait vmcnt(6); barrier; consume(b); issueA(b+2) [4 reg loads];
//   issueW(b+3) [DMA].
// Queue at top of iter b: [W(b),A(b)x4? -- precisely:
//   [W(b), A(b), W(b+1), A(b+1), W(b+2)] -> newer than {A(b),W(b)} = 6
// -> vmcnt(6) drains exactly A(b)+W(b); W flight 3 iters, A flight 2.
// Tail: vmcnt(5) at NT-2, vmcnt(0) at NT-1. A-overwrite is safe: consume(b)
// reads aCur before issueA(b+2) reloads the same set.
// W source-swizzle (DMA writes LDS linearly, m173): phys 16B-slot p gets
// src slot p^(row&7); read slot = (2lq+d)^(l16&7) -- R3-verified clean.
template<int K>
__device__ __forceinline__ void gemm_pipe(
    const short* __restrict__ A,
    const float* __restrict__ W,
    const float* __restrict__ bias,
    float* __restrict__ C,
    int N, int n0, char* smem)
{
  constexpr int NT = K / 32;

  const int t   = threadIdx.x;
  const int w   = t >> 6;
  const int l   = t & 63;
  const int l16 = l & 15;
  const int lq  = l >> 4;

  f32x4 acc[4][4];
  #pragma unroll
  for (int i = 0; i < 4; ++i)
    #pragma unroll
    for (int j = 0; j < 4; ++j) {
      f32x4 z = {0.f, 0.f, 0.f, 0.f};
      acc[i][j] = z;
    }

  // W DMA: wave op covers rows w*8 + (l>>3), phys slot l&7,
  // source slot (l&7)^(l>>3)  [row&7 == l>>3]
  const float* wsrc = W + (size_t)(n0 + w * 8 + (l >> 3)) * K
                        + (((l & 7) ^ (l >> 3)) << 2);
  auto issueW = [&](int bi) {
    gll16(wsrc + (bi << 5), smem + (bi & 3) * 8192 + w * 1024);
  };

  const short* ap = A + (size_t)(w * 64 + l16) * K + lq * 8;
  auto issueA = [&](int bi, short8 (&a)[4]) {
    #pragma unroll
    for (int mf = 0; mf < 4; ++mf)
      a[mf] = *(const short8*)(ap + (size_t)mf * 16 * K + (bi << 5));
  };

  auto consume = [&](int bi, short8 (&a)[4]) {
    const char* wb = smem + (bi & 3) * 8192;
    const int x = l16 & 7;
    #pragma unroll
    for (int nf = 0; nf < 4; ++nf) {
      const int row = nf * 16 + l16;
      f32x4 u = *(const f32x4*)(wb + row * 128 + (((2 * lq)     ^ x) << 4));
      f32x4 v = *(const f32x4*)(wb + row * 128 + (((2 * lq + 1) ^ x) << 4));
      short8 bb;
      #pragma unroll
      for (int i = 0; i < 4; ++i) { bb[i] = f2bf(u[i]); bb[i + 4] = f2bf(v[i]); }
      #pragma unroll
      for (int mf = 0; mf < 4; ++mf)
        acc[mf][nf] = __builtin_amdgcn_mfma_f32_16x16x32_bf16(a[mf], bb, acc[mf][nf], 0, 0, 0);
    }
  };

  short8 aA[4], aB[4];
  // prologue queue: [A0, W0, A1, W1, W2]
  issueA(0, aA);
  issueW(0);
  issueA(1, aB);
  issueW(1);
  issueW(2);

  auto step = [&](int b, short8 (&aCur)[4]) {
    if (b < NT - 2)       { asm volatile("s_waitcnt vmcnt(6)" ::: "memory"); }
    else if (b == NT - 2) { asm volatile("s_waitcnt vmcnt(5)" ::: "memory"); }
    else                  { asm volatile("s_waitcnt vmcnt(0)" ::: "memory"); }
    SCHED_FENCE();
    __builtin_amdgcn_s_barrier();     // W(b) landed for all waves
    SCHED_FENCE();
    consume(b, aCur);
    SCHED_FENCE();                    // keep A-reload after consume...
    if (b + 2 < NT) issueA(b + 2, aCur);
    SCHED_FENCE();                    // ...and before the W DMA (queue order)
    if (b + 3 < NT) issueW(b + 3);    // slot (b-1)&3: all waves done with it
  };

  for (int b = 0; b < NT; b += 2) {   // NT even (32 or 64)
    step(b,     aA);
    step(b + 1, aB);
  }
  __syncthreads();                     // before aliasing ring as epilogue

  // ---- epilogue: per-wave LDS transpose -> full-line f32x4 stores ----
  // acc layout: col = nf*16 + l16, row = mf*16 + lq*4 + r  [m89]
  float bvv[4];
  #pragma unroll
  for (int nf = 0; nf < 4; ++nf) bvv[nf] = bias[n0 + nf * 16 + l16];

  float* ep = (float*)(smem) + w * 16 * EPS;
  const int rr = lq;
  const int cc = l16 * 4;
  #pragma unroll
  for (int mf = 0; mf < 4; ++mf) {
    #pragma unroll
    for (int nf = 0; nf < 4; ++nf)
      #pragma unroll
      for (int r = 0; r < 4; ++r)
        ep[(lq * 4 + r) * EPS + nf * 16 + l16] = acc[mf][nf][r] + bvv[nf];
    #pragma unroll
    for (int i = 0; i < 4; ++i) {
      f32x4 vv = *(const f32x4*)&ep[(i * 4 + rr) * EPS + cc];
      *(f32x4*)&C[(size_t)(w * 64 + mf * 16 + i * 4 + rr) * N + n0 + cc] = vv;
    }
  }
}

__global__ __launch_bounds__(512, 4) void gru_gemms_kernel(
    const short* __restrict__ xbf, const short* __restrict__ hbf,
    const float* __restrict__ W_ih, const float* __restrict__ W_hh,
    const float* __restrict__ b_ih, const float* __restrict__ b_hh,
    float* __restrict__ gi, float* __restrict__ gh)
{
  __shared__ __align__(16) char smem[34816];   // max(4x8KB W ring, epilogue)
  const bool second = blockIdx.x >= 96;
  const int nb = second ? (int)blockIdx.x - 96 : (int)blockIdx.x;
  if (second)
    gemm_pipe<2048>(hbf, W_hh, b_hh, gh, 6144, nb * 64, smem);
  else
    gemm_pipe<1024>(xbf, W_ih, b_ih, gi, 6144, nb * 64, smem);
}

__global__ __launch_bounds__(512, 4) void logits_kernel(
    const short* __restrict__ hnbf, const float* __restrict__ fc_W,
    const float* __restrict__ fc_b, float* __restrict__ out)
{
  __shared__ __align__(16) char smem[34816];
  gemm_pipe<2048>(hnbf, fc_W, fc_b, out, 32000, (int)blockIdx.x * 64, smem);
}

__global__ void prep_kernel(const int* __restrict__ idx,
                            const float* __restrict__ hid,
                            const float* __restrict__ emb,
                            short* __restrict__ xbf, short* __restrict__ hbf)
{
  int i = blockIdx.x * blockDim.x + threadIdx.x;
  const int NX = 512 * 1024 / 4;
  const int NH = 512 * 2048 / 4;
  if (i < NX) {
    int b = i >> 8;
    int c = (i & 255) << 2;
    int row = idx[b];
    f32x4 v = *(const f32x4*)(emb + (size_t)row * 1024 + c);
    short4v o;
    #pragma unroll
    for (int j = 0; j < 4; ++j) o[j] = f2bf(v[j]);
    *(short4v*)(xbf + (size_t)b * 1024 + c) = o;
  } else if (i < NX + NH) {
    int j2 = i - NX;
    f32x4 v = *(const f32x4*)(hid + (size_t)j2 * 4);
    short4v o;
    #pragma unroll
    for (int j = 0; j < 4; ++j) o[j] = f2bf(v[j]);
    *(short4v*)(hbf + (size_t)j2 * 4) = o;
  }
}

__global__ void gates_kernel(const float* __restrict__ gi,
                             const float* __restrict__ gh,
                             const float* __restrict__ hid,
                             float* __restrict__ hnew,
                             short* __restrict__ hnbf)
{
  int i = blockIdx.x * blockDim.x + threadIdx.x;
  int b = i >> 9;
  int c = (i & 511) << 2;
  size_t gbase = (size_t)b * 6144 + c;
  f32x4 gir = *(const f32x4*)(gi + gbase);
  f32x4 giz = *(const f32x4*)(gi + gbase + 2048);
  f32x4 gin = *(const f32x4*)(gi + gbase + 4096);
  f32x4 ghr = *(const f32x4*)(gh + gbase);
  f32x4 ghz = *(const f32x4*)(gh + gbase + 2048);
  f32x4 ghn = *(const f32x4*)(gh + gbase + 4096);
  f32x4 hv  = *(const f32x4*)(hid + (size_t)b * 2048 + c);
  f32x4 hn;
  short4v hb;
  #pragma unroll
  for (int j = 0; j < 4; ++j) {
    float r = 1.f / (1.f + __expf(-(gir[j] + ghr[j])));
    float z = 1.f / (1.f + __expf(-(giz[j] + ghz[j])));
    float n = tanhf(gin[j] + r * ghn[j]);
    float o = (1.f - z) * n + z * hv[j];
    hn[j] = o;
    hb[j] = f2bf(o);
  }
  *(f32x4*)(hnew + (size_t)b * 2048 + c) = hn;
  *(short4v*)(hnbf + (size_t)b * 2048 + c) = hb;
}

extern "C" void kernel_launch(void* const* d_in, const int* in_sizes, int n_in,
                              void* d_out, int out_size, void* d_ws, size_t ws_size,
                              hipStream_t stream)
{
  const int*   idx   = (const int*)d_in[0];
  const float* hid   = (const float*)d_in[1];
  const float* emb   = (const float*)d_in[2];
  const float* W_ih  = (const float*)d_in[3];
  const float* W_hh  = (const float*)d_in[4];
  const float* b_ih  = (const float*)d_in[5];
  const float* b_hh  = (const float*)d_in[6];
  const float* fc_W  = (const float*)d_in[7];
  const float* fc_b  = (const float*)d_in[8];
  float* out = (float*)d_out;

  char* ws = (char*)d_ws;
  short* xbf  = (short*)(ws);
  short* hbf  = (short*)(ws + 1048576);
  short* hnbf = (short*)(ws + 3145728);
  float* gi   = (float*)(ws + 5242880);
  float* gh   = (float*)(ws + 17825792);

  prep_kernel<<<1536, 256, 0, stream>>>(idx, hid, emb, xbf, hbf);
  gru_gemms_kernel<<<192, 512, 0, stream>>>(xbf, hbf, W_ih, W_hh, b_ih, b_hh, gi, gh);
  gates_kernel<<<1024, 256, 0, stream>>>(gi, gh, hid, out + (size_t)512 * 32000, hnbf);
  logits_kernel<<<500, 512, 0, stream>>>(hnbf, fc_W, fc_b, out);
}